// Round 2
// baseline (174.440 us; speedup 1.0000x reference)
//
#include <hip/hip_runtime.h>
#include <cmath>

// Problem constants (fixed by the reference).
constexpr int B  = 4096;
constexpr int D  = 768;
constexpr int P  = 96;
constexpr int C  = 256;
constexpr int SD = 8;   // D / P

// ---- numpy fp32 emulation helpers ------------------------------------------
// numpy pairwise-sum base combine for 8 values (np.sum over last axis, n=8):
// ((q0+q1)+(q2+q3))+((q4+q5)+(q6+q7)), every add rounded fp32, no FMA.
__device__ __forceinline__ float tree8(float q0, float q1, float q2, float q3,
                                       float q4, float q5, float q6, float q7)
{
#pragma clang fp contract(off)
    return ((q0 + q1) + (q2 + q3)) + ((q4 + q5) + (q6 + q7));
}

// proba[b,p,c] = -((v_sq - 2*vc) + c_sq), all fp32 roundings in numpy's order.
// vc = einsum over d=8: npyv(SSE2) sum-of-products order:
//   p_i = fl(v_i*c_i); l_j = fl(p_j + p_{j+4}); vc = fl(fl(l0+l2) + fl(l1+l3))
__device__ __forceinline__ float proba_at(const float* __restrict__ cbf,
                                          const float* __restrict__ csq,
                                          int c, float4 va, float4 vb, float vsq)
{
#pragma clang fp contract(off)
    float4 ca = ((const float4*)cbf)[2 * c];
    float4 cb = ((const float4*)cbf)[2 * c + 1];
    float p0 = va.x * ca.x, p1 = va.y * ca.y, p2 = va.z * ca.z, p3 = va.w * ca.w;
    float p4 = vb.x * cb.x, p5 = vb.y * cb.y, p6 = vb.z * cb.z, p7 = vb.w * cb.w;
    float l0 = p0 + p4, l1 = p1 + p5, l2 = p2 + p6, l3 = p3 + p7;
    float vc = (l0 + l2) + (l1 + l3);
    float tt = vsq - 2.0f * vc;   // fl(v_sq - fl(2*vc)); *2 exact
    float u  = tt + csq[c];       // fl(tt + c_sq)
    return -u;                    // negation exact
}

// One block: partition p x 256 batch rows; one thread per (b,p) search.
__global__ __launch_bounds__(256, 2)
void pq_np_emul_kernel(const float* __restrict__ vecs,
                       const float* __restrict__ codebook,
                       float* __restrict__ out)
{
#pragma clang fp contract(off)
    __shared__ float cbf[C * SD];  // 8 KB codebook[p]
    __shared__ float csq[C];       // 1 KB ||c||^2 (fp32, numpy order)

    const int p = blockIdx.x;
    const int t = threadIdx.x;
    const int b = blockIdx.y * 256 + t;

    // cooperative codebook[p] load: 2048 floats
    const float4* src = (const float4*)(codebook + (size_t)p * C * SD);
    float4 s0 = src[t];
    float4 s1 = src[t + 256];
    ((float4*)cbf)[t]       = s0;
    ((float4*)cbf)[t + 256] = s1;
    __syncthreads();

    // c_sq per centroid, numpy fp32 order (square each elem, tree8)
    {
        const float* cc = cbf + t * SD;
        float q0 = cc[0]*cc[0], q1 = cc[1]*cc[1], q2 = cc[2]*cc[2], q3 = cc[3]*cc[3];
        float q4 = cc[4]*cc[4], q5 = cc[5]*cc[5], q6 = cc[6]*cc[6], q7 = cc[7]*cc[7];
        csq[t] = tree8(q0,q1,q2,q3,q4,q5,q6,q7);
    }
    __syncthreads();

    // this thread's sub-vector and v_sq (numpy fp32 order)
    const float* vptr = vecs + (size_t)b * D + (size_t)p * SD;
    float4 va = ((const float4*)vptr)[0];
    float4 vb = ((const float4*)vptr)[1];
    float vsq;
    {
        float q0 = va.x*va.x, q1 = va.y*va.y, q2 = va.z*va.z, q3 = va.w*va.w;
        float q4 = vb.x*vb.x, q5 = vb.y*vb.y, q6 = vb.z*vb.z, q7 = vb.w*vb.w;
        vsq = tree8(q0,q1,q2,q3,q4,q5,q6,q7);
    }

    // pass 1: argmax(proba) with top-2 tracking, first index wins ties
    float best = -3.402823466e38f, second = -3.402823466e38f;
    int bi = 0;
    for (int c = 0; c < C; ++c) {
        float pr = proba_at(cbf, csq, c, va, vb, vsq);
        if (pr > best)        { second = best; best = pr; bi = c; }
        else if (pr > second) { second = pr; }
    }
    int idx = bi;

    // Rare near-tie: emulate the full fp32 softmax. exp/division rounding can
    // make assign[j] == assign[imax] for j < imax; np.argmax then picks j.
    if (best - second <= 1.0e-6f) {
        float m = best;  // np.max(proba) — identical bits by construction
        // denominator: numpy pairwise sum over 256 = pairwise(128)+pairwise(128),
        // each 128 = 8 accumulators r[j] += e[8k+j], combined with tree8.
        float r0[8] = {0,0,0,0,0,0,0,0};
        float r1[8] = {0,0,0,0,0,0,0,0};
        for (int cg = 0; cg < 16; ++cg) {
            #pragma unroll
            for (int j = 0; j < 8; ++j) {
                float pr = proba_at(cbf, csq, cg * 8 + j, va, vb, vsq);
                r0[j] += expf(pr - m);
            }
        }
        for (int cg = 16; cg < 32; ++cg) {
            #pragma unroll
            for (int j = 0; j < 8; ++j) {
                float pr = proba_at(cbf, csq, cg * 8 + j, va, vb, vsq);
                r1[j] += expf(pr - m);
            }
        }
        float sum = tree8(r0[0],r0[1],r0[2],r0[3],r0[4],r0[5],r0[6],r0[7])
                  + tree8(r1[0],r1[1],r1[2],r1[3],r1[4],r1[5],r1[6],r1[7]);
        // argmax over assign = e / sum, ascending, strict '>' (first tie wins)
        float abest = -1.0f;
        int   ai    = 0;
        for (int c = 0; c < C; ++c) {
            float pr = proba_at(cbf, csq, c, va, vb, vsq);
            float e  = expf(pr - m);
            float a  = e / sum;                 // IEEE fp32 divide
            if (a > abest) { abest = a; ai = c; }
        }
        idx = ai;
    }

    // gather winning centroid and store
    float4 o0 = ((const float4*)cbf)[2 * idx];
    float4 o1 = ((const float4*)cbf)[2 * idx + 1];
    float4* op = (float4*)(out + (size_t)b * D + (size_t)p * SD);
    op[0] = o0;
    op[1] = o1;
}

extern "C" void kernel_launch(void* const* d_in, const int* in_sizes, int n_in,
                              void* d_out, int out_size, void* d_ws, size_t ws_size,
                              hipStream_t stream)
{
    const float* vecs     = (const float*)d_in[0];  // [B, D] fp32
    const float* codebook = (const float*)d_in[1];  // [P, C, SD] fp32
    float*       out      = (float*)d_out;          // [B, D] fp32

    dim3 grid(P, B / 256);   // (96, 16)
    dim3 block(256);
    pq_np_emul_kernel<<<grid, block, 0, stream>>>(vecs, codebook, out);
}